// Round 5
// baseline (95.707 us; speedup 1.0000x reference)
//
#include <hip/hip_runtime.h>

// CenterNeighAtt on MI355X. E=512, F=256, R=4.
//
// Exact math simplifications (validated R1-R4, absmax ~5e-4 vs 2.3e-3 threshold):
//  * alpha = softmax_j(sum_i scores[i,j]) is uniform 1/E: sum_i attention[i,j,f]==1,
//    so column sums of scores are constant in j. lin_w/lin_b are dead inputs.
//  * No max-subtraction in softmaxes: logits bounded (~20), exp far below f32 overflow.
//
// R5: (R4 post-mortem: ~23us real work vs 44.8us measured -> launch gaps + 2 waves/SIMD
// occupancy). NCH=16 -> 1024 blocks (4 waves/SIMD); h-chunk register-staged so the hot
// loop is pure LDS-broadcast + VALU; kC2 folded into kC via split-K last-block finisher.

#define EE 512
#define FF 256
#define RRR 4
#define LOG2E 1.44269504088896340736f
#define TT 8     // rows per block (kB: j's, kC: i's)
#define NCH 16   // reduction-axis chunks
#define CLEN 32  // 512 / NCH

// --- kA: zero Z/Hp/cnt; s[i,:] = softmax_j(sum_r adj[r,i,:]); alpha --------
__global__ __launch_bounds__(256) void kA(const float* __restrict__ adj,
                                          float* __restrict__ s,
                                          float* __restrict__ Z,
                                          float* __restrict__ Hp,
                                          float* __restrict__ out,
                                          int* __restrict__ cnt) {
    const int i = blockIdx.x;
    const int t = threadIdx.x;
    Z[i * 256 + t]  = 0.f;           // E*F floats, covered exactly by grid
    Hp[i * 256 + t] = 0.f;
    if (i == 0) {
        out[EE * FF + t]       = 1.0f / EE;   // alpha: softmax of constant = uniform
        out[EE * FF + 256 + t] = 1.0f / EE;
        if (t < EE / TT) cnt[t] = 0;          // finisher counters
    }
    const float* base = adj + (size_t)i * EE;
    float t0 = 0.f, t1 = 0.f;
#pragma unroll
    for (int r = 0; r < RRR; ++r) {
        t0 += base[(size_t)r * EE * EE + t];
        t1 += base[(size_t)r * EE * EE + t + 256];
    }
    const float e0 = __expf(t0);
    const float e1 = __expf(t1);
    __shared__ float red[256];
    red[t] = e0 + e1;
    __syncthreads();
    for (int off = 128; off > 0; off >>= 1) {
        if (t < off) red[t] += red[t + off];
        __syncthreads();
    }
    const float inv = 1.0f / red[0];
    s[(size_t)i * EE + t]       = e0 * inv;
    s[(size_t)i * EE + t + 256] = e1 * inv;
}

// --- kB: Z[j,f] += sum_{i in chunk c} exp2(lrelu(s*h_if*h_jf)*log2e) -------
__global__ __launch_bounds__(256) void kB(const float* __restrict__ h,
                                          const float* __restrict__ s,
                                          float* __restrict__ Z) {
    const int j0 = blockIdx.x * TT;   // 64 j-groups
    const int i0 = blockIdx.y * CLEN; // 16 i-chunks
    const int f  = threadIdx.x;
    __shared__ float4 sl4[CLEN * 2];  // s[i0+ii][j0..j0+7] as two float4 per row
    if (f < CLEN * 2)
        sl4[f] = ((const float4*)(s + (size_t)(i0 + (f >> 1)) * EE + j0))[f & 1];
    __syncthreads();
    float hv[CLEN];                   // register-staged h chunk: no loads in hot loop
#pragma unroll
    for (int ii = 0; ii < CLEN; ++ii) hv[ii] = h[(size_t)(i0 + ii) * FF + f];
    float hj[TT], Zl[TT];
#pragma unroll
    for (int tj = 0; tj < TT; ++tj) {
        hj[tj] = h[(size_t)(j0 + tj) * FF + f] * LOG2E;  // fold log2e
        Zl[tj] = 0.f;
    }
#pragma unroll 4
    for (int ii = 0; ii < CLEN; ++ii) {
        const float4 sa = sl4[ii * 2];       // ds_read_b128 broadcast (conflict-free)
        const float4 sb = sl4[ii * 2 + 1];
        const float sv[8] = {sa.x, sa.y, sa.z, sa.w, sb.x, sb.y, sb.z, sb.w};
#pragma unroll
        for (int tj = 0; tj < TT; ++tj) {
            const float y = sv[tj] * hv[ii] * hj[tj];
            Zl[tj] += __builtin_amdgcn_exp2f(fmaxf(y, 0.2f * y));  // lrelu folded
        }
    }
#pragma unroll
    for (int tj = 0; tj < TT; ++tj)
        atomicAdd(&Z[(size_t)(j0 + tj) * FF + f], Zl[tj]);
}

// --- kC: Hp[i,f] += sum_{j in chunk} (h_jf*rcp(Z_jf))*exp2(...);
//         last chunk-block per i-group applies ELU and writes out ----------
__global__ __launch_bounds__(256) void kC(const float* __restrict__ h,
                                          const float* __restrict__ s,
                                          const float* __restrict__ Z,
                                          float* __restrict__ Hp,
                                          float* __restrict__ out,
                                          int* __restrict__ cnt) {
    const int i0 = blockIdx.x * TT;   // 64 i-groups
    const int j0 = blockIdx.y * CLEN; // 16 j-chunks
    const int f  = threadIdx.x;
    __shared__ __align__(16) float slf[CLEN * TT];   // [jj][ti] transposed s-tile
    {   // coalesced global read: lane -> (ti = f>>5, jj = f&31)
        const int ti = f >> 5, jj = f & 31;
        slf[jj * TT + ti] = s[(size_t)(i0 + ti) * EE + j0 + jj];
    }
    __syncthreads();
    float hjv[CLEN], gj[CLEN];        // register-staged h row + g = h/Z
#pragma unroll
    for (int jj = 0; jj < CLEN; ++jj) {
        hjv[jj] = h[(size_t)(j0 + jj) * FF + f];
        gj[jj]  = hjv[jj] * __builtin_amdgcn_rcpf(Z[(size_t)(j0 + jj) * FF + f]);
    }
    float hl[TT], acc[TT];
#pragma unroll
    for (int ti = 0; ti < TT; ++ti) {
        hl[ti] = h[(size_t)(i0 + ti) * FF + f] * LOG2E;
        acc[ti] = 0.f;
    }
#pragma unroll 4
    for (int jj = 0; jj < CLEN; ++jj) {
        const float4 sa = ((const float4*)slf)[jj * 2];
        const float4 sb = ((const float4*)slf)[jj * 2 + 1];
        const float sv[8] = {sa.x, sa.y, sa.z, sa.w, sb.x, sb.y, sb.z, sb.w};
#pragma unroll
        for (int ti = 0; ti < TT; ++ti) {
            const float y = sv[ti] * hl[ti] * hjv[jj];
            acc[ti] = fmaf(__builtin_amdgcn_exp2f(fmaxf(y, 0.2f * y)), gj[jj], acc[ti]);
        }
    }
#pragma unroll
    for (int ti = 0; ti < TT; ++ti)
        atomicAdd(&Hp[(size_t)(i0 + ti) * FF + f], acc[ti]);

    // split-K finisher: 16th block for this i-group applies ELU.
    __threadfence();                  // release: my Hp adds visible before counter
    __syncthreads();
    __shared__ int sdone;
    if (f == 0) sdone = (atomicAdd(&cnt[blockIdx.x], 1) == NCH - 1) ? 1 : 0;
    __syncthreads();
    if (sdone) {
        __threadfence();              // acquire: other blocks' adds visible
#pragma unroll
        for (int ti = 0; ti < TT; ++ti) {
            const float a = Hp[(size_t)(i0 + ti) * FF + f];
            out[(size_t)(i0 + ti) * FF + f] = (a > 0.f) ? a : (__expf(a) - 1.0f);
        }
    }
}

extern "C" void kernel_launch(void* const* d_in, const int* in_sizes, int n_in,
                              void* d_out, int out_size, void* d_ws, size_t ws_size,
                              hipStream_t stream) {
    const float* h   = (const float*)d_in[0];  // [E,F]
    const float* adj = (const float*)d_in[1];  // [R,E,E]
    // lin_w / lin_b mathematically dead (alpha uniform).

    float* s  = (float*)d_ws;                  // 1 MB
    float* Z  = s + (size_t)EE * EE;           // 512 KB
    float* Hp = Z + (size_t)EE * FF;           // 512 KB
    int*  cnt = (int*)(Hp + (size_t)EE * FF);  // 64 ints (total ~2 MB)
    float* out = (float*)d_out;

    kA<<<EE, 256, 0, stream>>>(adj, s, Z, Hp, out, cnt);
    kB<<<dim3(EE / TT, NCH), 256, 0, stream>>>(h, s, Z);
    kC<<<dim3(EE / TT, NCH), 256, 0, stream>>>(h, s, Z, Hp, out, cnt);
}